// Round 1
// baseline (1238.577 us; speedup 1.0000x reference)
//
#include <hip/hip_runtime.h>
#include <math.h>

#define N_IN 128

__device__ __forceinline__ float leaky01(float x) { return x >= 0.f ? x : 0.01f * x; }
__device__ __forceinline__ float leaky02(float x) { return x >= 0.f ? x : 0.2f * x; }

// ---------------- CSR build ----------------
__global__ void k_count(const int* __restrict__ edst, int* __restrict__ deg, int E) {
    int e = blockIdx.x * 256 + threadIdx.x;
    if (e < E) atomicAdd(&deg[edst[e]], 1);
}

__global__ void k_scan(const int* __restrict__ deg, int* __restrict__ rowptr, int n) {
    __shared__ int s[256];
    __shared__ int carry;
    int t = threadIdx.x;
    if (t == 0) { carry = 0; rowptr[0] = 0; }
    __syncthreads();
    for (int base = 0; base < n; base += 256) {
        int v = (base + t < n) ? deg[base + t] : 0;
        s[t] = v;
        __syncthreads();
        for (int off = 1; off < 256; off <<= 1) {
            int x = (t >= off) ? s[t - off] : 0;
            __syncthreads();
            s[t] += x;
            __syncthreads();
        }
        if (base + t < n) rowptr[base + t + 1] = carry + s[t];
        __syncthreads();
        if (t == 0) carry += s[255];
        __syncthreads();
    }
}

__global__ void k_fill(const int* __restrict__ esrc, const int* __restrict__ edst,
                       const float* __restrict__ ew, const int* __restrict__ rowptr,
                       int* __restrict__ cursor, int* __restrict__ eid,
                       int* __restrict__ csrc, float* __restrict__ clew, int E) {
    int e = blockIdx.x * 256 + threadIdx.x;
    if (e >= E) return;
    int d = edst[e];
    int slot = rowptr[d] + atomicAdd(&cursor[d], 1);
    eid[slot] = e;
    csrc[slot] = esrc[e];
    clew[slot] = log1pf(ew[e]);
}

// deterministic order: insertion-sort each node's segment by edge id
__global__ void k_sortseg(const int* __restrict__ rowptr, int* __restrict__ eid,
                          int* __restrict__ csrc, float* __restrict__ clew, int n) {
    int v = blockIdx.x * 256 + threadIdx.x;
    if (v >= n) return;
    int b = rowptr[v], e = rowptr[v + 1];
    for (int i = b + 1; i < e; i++) {
        int ke = eid[i], ks = csrc[i];
        float kl = clew[i];
        int j = i - 1;
        while (j >= b && eid[j] > ke) {
            eid[j + 1] = eid[j]; csrc[j + 1] = csrc[j]; clew[j + 1] = clew[j];
            j--;
        }
        eid[j + 1] = ke; csrc[j + 1] = ks; clew[j + 1] = kl;
    }
}

// ---------------- fp32 GEMM: C[N,M] = X[N,K] @ W[M,K]^T ----------------
// block 256 threads, tile 128 rows x 128 cols, 8x8 micro-tile, KT=8
__global__ __launch_bounds__(256) void k_gemm(const float* __restrict__ X,
                                              const float* __restrict__ W,
                                              float* __restrict__ C,
                                              int N, int K, int M) {
    __shared__ float Xs[8][132];
    __shared__ float Ws[8][132];
    int r0 = blockIdx.y * 128;
    int c0 = blockIdx.x * 128;
    int t = threadIdx.x;
    int ty = t >> 4, tx = t & 15;

    float acc[8][8];
#pragma unroll
    for (int i = 0; i < 8; i++)
#pragma unroll
        for (int j = 0; j < 8; j++) acc[i][j] = 0.f;

    int lr = t >> 1;            // 0..127
    int lk = (t & 1) * 4;       // 0 or 4
    bool xok = (r0 + lr) < N;
    const float* Xp = X + (size_t)(r0 + lr) * K + lk;
    const float* Wp = W + (size_t)(c0 + lr) * K + lk;

    for (int k0 = 0; k0 < K; k0 += 8) {
        float4 xv = xok ? *(const float4*)(Xp + k0) : make_float4(0.f, 0.f, 0.f, 0.f);
        float4 wv = *(const float4*)(Wp + k0);
        __syncthreads();
        Xs[lk + 0][lr] = xv.x; Xs[lk + 1][lr] = xv.y; Xs[lk + 2][lr] = xv.z; Xs[lk + 3][lr] = xv.w;
        Ws[lk + 0][lr] = wv.x; Ws[lk + 1][lr] = wv.y; Ws[lk + 2][lr] = wv.z; Ws[lk + 3][lr] = wv.w;
        __syncthreads();
#pragma unroll
        for (int k = 0; k < 8; k++) {
            float4 a0 = *(const float4*)&Xs[k][ty * 8];
            float4 a1 = *(const float4*)&Xs[k][ty * 8 + 4];
            float4 b0 = *(const float4*)&Ws[k][tx * 8];
            float4 b1 = *(const float4*)&Ws[k][tx * 8 + 4];
            float av[8] = {a0.x, a0.y, a0.z, a0.w, a1.x, a1.y, a1.z, a1.w};
            float bv[8] = {b0.x, b0.y, b0.z, b0.w, b1.x, b1.y, b1.z, b1.w};
#pragma unroll
            for (int i = 0; i < 8; i++)
#pragma unroll
                for (int j = 0; j < 8; j++) acc[i][j] += av[i] * bv[j];
        }
    }

#pragma unroll
    for (int i = 0; i < 8; i++) {
        int row = r0 + ty * 8 + i;
        if (row < N) {
            float4 v0 = make_float4(acc[i][0], acc[i][1], acc[i][2], acc[i][3]);
            float4 v1 = make_float4(acc[i][4], acc[i][5], acc[i][6], acc[i][7]);
            *(float4*)&C[(size_t)row * M + c0 + tx * 8] = v0;
            *(float4*)&C[(size_t)row * M + c0 + tx * 8 + 4] = v1;
        }
    }
}

// ---------------- qa[n,h] = sum_f feat[n,h*F+f] * a[f] ----------------
template <int H, int F>
__global__ __launch_bounds__(H * F) void k_qa(const float* __restrict__ feat,
                                              const float* __restrict__ a,
                                              float* __restrict__ qa, int N) {
    constexpr int M = H * F;
    int n = blockIdx.x, t = threadIdx.x;
    __shared__ float s[M];
    float p = feat[(size_t)n * M + t] * a[t & (F - 1)];
    s[t] = p;
    __syncthreads();
    for (int off = F / 2; off > 0; off >>= 1) {
        if ((t & (F - 1)) < off) s[t] += s[t + off];
        __syncthreads();
    }
    if ((t & (F - 1)) == 0) qa[n * H + t / F] = s[t];
}

// ---------------- GAT aggregation: one block per dst node ----------------
template <int H, int F, bool LOUT>
__global__ __launch_bounds__(H * F) void k_agg(const float* __restrict__ feat,
                                               const float* __restrict__ qa,
                                               const float* __restrict__ bias,
                                               const int* __restrict__ rowptr,
                                               const int* __restrict__ csr_src,
                                               const float* __restrict__ csr_lew,
                                               float* __restrict__ out, int N) {
    constexpr int M = H * F;
    int n = blockIdx.x, t = threadIdx.x;
    __shared__ float s_qan[H], s_m[H], s_inv[H];
    __shared__ float red_m[M * H], red_s[M * H];
    __shared__ int sh_src[64];
    __shared__ float sh_alpha[64 * H];

    int beg = rowptr[n];
    int deg = rowptr[n + 1] - beg;
    if (t < H) s_qan[t] = qa[n * H + t];
    __syncthreads();

    // phase 1: online softmax stats per head
    float m_l[H], s_l[H];
#pragma unroll
    for (int h = 0; h < H; h++) { m_l[h] = -1e30f; s_l[h] = 0.f; }
    for (int i = t; i < deg; i += M) {
        int src = csr_src[beg + i];
        float lw = csr_lew[beg + i];
#pragma unroll
        for (int h = 0; h < H; h++) {
            float sc = leaky01(qa[src * H + h] + s_qan[h] + lw);
            if (sc > m_l[h]) {
                s_l[h] = s_l[h] * __expf(m_l[h] - sc) + 1.f;
                m_l[h] = sc;
            } else {
                s_l[h] += __expf(sc - m_l[h]);
            }
        }
    }
#pragma unroll
    for (int h = 0; h < H; h++) { red_m[t * H + h] = m_l[h]; red_s[t * H + h] = s_l[h]; }
    __syncthreads();
    for (int st = M / 2; st > 0; st >>= 1) {
        if (t < st) {
#pragma unroll
            for (int h = 0; h < H; h++) {
                float m1 = red_m[t * H + h], s1 = red_s[t * H + h];
                float m2 = red_m[(t + st) * H + h], s2 = red_s[(t + st) * H + h];
                float mm = fmaxf(m1, m2);
                red_m[t * H + h] = mm;
                red_s[t * H + h] = s1 * __expf(m1 - mm) + s2 * __expf(m2 - mm);
            }
        }
        __syncthreads();
    }
    if (t < H) {
        s_m[t] = red_m[t];
        s_inv[t] = 1.f / fmaxf(red_s[t], 1e-20f);
    }
    __syncthreads();

    // phase 2: weighted aggregation, chunked 64 edges at a time
    float acc = 0.f;
    const int hh = t / F;
    for (int c0 = 0; c0 < deg; c0 += 64) {
        int cn = min(64, deg - c0);
        if (t < cn) {
            int src = csr_src[beg + c0 + t];
            float lw = csr_lew[beg + c0 + t];
            sh_src[t] = src;
#pragma unroll
            for (int h = 0; h < H; h++) {
                float sc = leaky01(qa[src * H + h] + s_qan[h] + lw);
                sh_alpha[t * H + h] = __expf(sc - s_m[h]) * s_inv[h];
            }
        }
        __syncthreads();
        for (int i = 0; i < cn; i++)
            acc += sh_alpha[i * H + hh] * feat[(size_t)sh_src[i] * M + t];
        __syncthreads();
    }
    float r = acc + bias[t];
    if (LOUT) r = leaky01(r);
    out[(size_t)n * M + t] = r;
}

// ---------------- predictor: thread per pair ----------------
__global__ __launch_bounds__(256) void k_pred(const float* __restrict__ h2,
                                              const int* __restrict__ ps, const int* __restrict__ pd,
                                              const int* __restrict__ ns, const int* __restrict__ nd,
                                              const float* __restrict__ W1, const float* __restrict__ b1,
                                              const float* __restrict__ W2, const float* __restrict__ b2,
                                              const float* __restrict__ W3, const float* __restrict__ b3,
                                              float* __restrict__ out, int npos, int nneg) {
    int p = blockIdx.x * 256 + threadIdx.x;
    if (p >= npos + nneg) return;
    int s, d;
    if (p < npos) { s = ps[p]; d = pd[p]; }
    else          { s = ns[p - npos]; d = nd[p - npos]; }
    const float4* hs4 = (const float4*)(h2 + (size_t)s * 128);
    const float4* hd4 = (const float4*)(h2 + (size_t)d * 128);

    float t1[64];
#pragma unroll
    for (int j = 0; j < 64; j++) t1[j] = b1[j];

    for (int kc = 0; kc < 32; kc += 2) {   // 8 z-values per iter
        float4 za = hs4[kc], zb = hd4[kc];
        float4 zc = hs4[kc + 1], zd = hd4[kc + 1];
        float z[8] = {za.x * zb.x, za.y * zb.y, za.z * zb.z, za.w * zb.w,
                      zc.x * zd.x, zc.y * zd.y, zc.z * zd.z, zc.w * zd.w};
        const float* wrow = W1 + kc * 4;   // uniform address -> s_load
#pragma unroll
        for (int j = 0; j < 64; j++) {
            float a = t1[j];
#pragma unroll
            for (int q = 0; q < 8; q++) a += z[q] * wrow[j * 128 + q];
            t1[j] = a;
        }
    }

    float t2[32];
#pragma unroll
    for (int i = 0; i < 32; i++) t2[i] = b2[i];
#pragma unroll
    for (int j = 0; j < 64; j++) {
        float v = leaky02(t1[j]);
#pragma unroll
        for (int i = 0; i < 32; i++) t2[i] += v * W2[i * 64 + j];
    }
    float o = b3[0];
#pragma unroll
    for (int i = 0; i < 32; i++) o += leaky02(t2[i]) * W3[i];
    out[p] = o;
}

extern "C" void kernel_launch(void* const* d_in, const int* in_sizes, int n_in,
                              void* d_out, int out_size, void* d_ws, size_t ws_size,
                              hipStream_t stream) {
    const float* x    = (const float*)d_in[0];
    const float* ew   = (const float*)d_in[1];
    const int* esrc   = (const int*)d_in[2];
    const int* edst   = (const int*)d_in[3];
    const int* pos_s  = (const int*)d_in[4];
    const int* pos_d  = (const int*)d_in[5];
    const int* neg_s  = (const int*)d_in[6];
    const int* neg_d  = (const int*)d_in[7];
    const float* W0 = (const float*)d_in[8];
    const float* a0 = (const float*)d_in[9];
    const float* b0 = (const float*)d_in[10];
    const float* W1 = (const float*)d_in[11];
    const float* a1 = (const float*)d_in[12];
    const float* b1 = (const float*)d_in[13];
    const float* W2 = (const float*)d_in[14];
    const float* a2 = (const float*)d_in[15];
    const float* b2 = (const float*)d_in[16];
    const float* pW1 = (const float*)d_in[17];
    const float* pb1 = (const float*)d_in[18];
    const float* pW2 = (const float*)d_in[19];
    const float* pb2 = (const float*)d_in[20];
    const float* pW3 = (const float*)d_in[21];
    const float* pb3 = (const float*)d_in[22];

    const int N = in_sizes[0] / N_IN;   // 25000
    const int E = in_sizes[1];          // 400000
    const int NP = in_sizes[4];         // 100000

    // workspace layout
    size_t off = 0;
    auto alloc = [&](size_t bytes) {
        void* p = (char*)d_ws + off;
        off += (bytes + 255) & ~(size_t)255;
        return p;
    };
    int* deg      = (int*)alloc((size_t)N * 4);
    int* cursor   = (int*)alloc((size_t)N * 4);
    int* rowptr   = (int*)alloc((size_t)(N + 1) * 4);
    int* csr_eid  = (int*)alloc((size_t)E * 4);
    int* csr_src  = (int*)alloc((size_t)E * 4);
    float* csr_lew = (float*)alloc((size_t)E * 4);
    float* qa     = (float*)alloc((size_t)N * 4 * 4);
    float* A      = (float*)alloc((size_t)N * 256 * 4);
    float* B      = (float*)alloc((size_t)N * 256 * 4);
    (void)ws_size; (void)n_in; (void)out_size;

    float* out_pred = (float*)d_out;              // [200000]
    float* emb      = (float*)d_out + 2 * NP;     // [25000 x 128]

    hipMemsetAsync(deg, 0, (size_t)N * 4, stream);
    hipMemsetAsync(cursor, 0, (size_t)N * 4, stream);

    int eb = (E + 255) / 256;
    k_count<<<eb, 256, 0, stream>>>(edst, deg, E);
    k_scan<<<1, 256, 0, stream>>>(deg, rowptr, N);
    k_fill<<<eb, 256, 0, stream>>>(esrc, edst, ew, rowptr, cursor, csr_eid, csr_src, csr_lew, E);
    k_sortseg<<<(N + 255) / 256, 256, 0, stream>>>(rowptr, csr_eid, csr_src, csr_lew, N);

    int rb = (N + 127) / 128;   // 196

    // layer 0: K=128, M=256
    k_gemm<<<dim3(2, rb), 256, 0, stream>>>(x, W0, A, N, 128, 256);
    k_qa<4, 64><<<N, 256, 0, stream>>>(A, a0, qa, N);
    k_agg<4, 64, true><<<N, 256, 0, stream>>>(A, qa, b0, rowptr, csr_src, csr_lew, B, N);

    // layer 1: K=256, M=256
    k_gemm<<<dim3(2, rb), 256, 0, stream>>>(B, W1, A, N, 256, 256);
    k_qa<4, 64><<<N, 256, 0, stream>>>(A, a1, qa, N);
    k_agg<4, 64, true><<<N, 256, 0, stream>>>(A, qa, b1, rowptr, csr_src, csr_lew, B, N);

    // layer 2: K=256, M=128
    k_gemm<<<dim3(1, rb), 256, 0, stream>>>(B, W2, A, N, 256, 128);
    k_qa<1, 128><<<N, 128, 0, stream>>>(A, a2, qa, N);
    k_agg<1, 128, false><<<N, 128, 0, stream>>>(A, qa, b2, rowptr, csr_src, csr_lew, emb, N);

    // predictor on 2*NP pairs
    k_pred<<<(2 * NP + 255) / 256, 256, 0, stream>>>(emb, pos_s, pos_d, neg_s, neg_d,
                                                     pW1, pb1, pW2, pb2, pW3, pb3,
                                                     out_pred, NP, NP);
}

// Round 2
// 745.185 us; speedup vs baseline: 1.6621x; 1.6621x over previous
//
#include <hip/hip_runtime.h>
#include <math.h>

#define N_IN 128

__device__ __forceinline__ float leaky01(float x) { return x >= 0.f ? x : 0.01f * x; }
__device__ __forceinline__ float leaky02(float x) { return x >= 0.f ? x : 0.2f * x; }

// ---------------- CSR build ----------------
__global__ void k_count(const int* __restrict__ edst, int* __restrict__ deg, int E) {
    int e = blockIdx.x * 256 + threadIdx.x;
    if (e < E) atomicAdd(&deg[edst[e]], 1);
}

__global__ void k_scan(const int* __restrict__ deg, int* __restrict__ rowptr, int n) {
    __shared__ int s[256];
    __shared__ int carry;
    int t = threadIdx.x;
    if (t == 0) { carry = 0; rowptr[0] = 0; }
    __syncthreads();
    for (int base = 0; base < n; base += 256) {
        int v = (base + t < n) ? deg[base + t] : 0;
        s[t] = v;
        __syncthreads();
        for (int off = 1; off < 256; off <<= 1) {
            int x = (t >= off) ? s[t - off] : 0;
            __syncthreads();
            s[t] += x;
            __syncthreads();
        }
        if (base + t < n) rowptr[base + t + 1] = carry + s[t];
        __syncthreads();
        if (t == 0) carry += s[255];
        __syncthreads();
    }
}

__global__ void k_fill(const int* __restrict__ esrc, const int* __restrict__ edst,
                       const float* __restrict__ ew, const int* __restrict__ rowptr,
                       int* __restrict__ cursor, int* __restrict__ eid,
                       int* __restrict__ csrc, float* __restrict__ clew, int E) {
    int e = blockIdx.x * 256 + threadIdx.x;
    if (e >= E) return;
    int d = edst[e];
    int slot = rowptr[d] + atomicAdd(&cursor[d], 1);
    eid[slot] = e;
    csrc[slot] = esrc[e];
    clew[slot] = log1pf(ew[e]);
}

// deterministic order: insertion-sort each node's segment by edge id
__global__ void k_sortseg(const int* __restrict__ rowptr, int* __restrict__ eid,
                          int* __restrict__ csrc, float* __restrict__ clew, int n) {
    int v = blockIdx.x * 256 + threadIdx.x;
    if (v >= n) return;
    int b = rowptr[v], e = rowptr[v + 1];
    for (int i = b + 1; i < e; i++) {
        int ke = eid[i], ks = csrc[i];
        float kl = clew[i];
        int j = i - 1;
        while (j >= b && eid[j] > ke) {
            eid[j + 1] = eid[j]; csrc[j + 1] = csrc[j]; clew[j + 1] = clew[j];
            j--;
        }
        eid[j + 1] = ke; csrc[j + 1] = ks; clew[j + 1] = kl;
    }
}

// ---------------- fp32 GEMM: C[N,M] = X[N,K] @ W[M,K]^T ----------------
__global__ __launch_bounds__(256) void k_gemm(const float* __restrict__ X,
                                              const float* __restrict__ W,
                                              float* __restrict__ C,
                                              int N, int K, int M) {
    __shared__ float Xs[8][132];
    __shared__ float Ws[8][132];
    int r0 = blockIdx.y * 128;
    int c0 = blockIdx.x * 128;
    int t = threadIdx.x;
    int ty = t >> 4, tx = t & 15;

    float acc[8][8];
#pragma unroll
    for (int i = 0; i < 8; i++)
#pragma unroll
        for (int j = 0; j < 8; j++) acc[i][j] = 0.f;

    int lr = t >> 1;            // 0..127
    int lk = (t & 1) * 4;       // 0 or 4
    bool xok = (r0 + lr) < N;
    const float* Xp = X + (size_t)(r0 + lr) * K + lk;
    const float* Wp = W + (size_t)(c0 + lr) * K + lk;

    for (int k0 = 0; k0 < K; k0 += 8) {
        float4 xv = xok ? *(const float4*)(Xp + k0) : make_float4(0.f, 0.f, 0.f, 0.f);
        float4 wv = *(const float4*)(Wp + k0);
        __syncthreads();
        Xs[lk + 0][lr] = xv.x; Xs[lk + 1][lr] = xv.y; Xs[lk + 2][lr] = xv.z; Xs[lk + 3][lr] = xv.w;
        Ws[lk + 0][lr] = wv.x; Ws[lk + 1][lr] = wv.y; Ws[lk + 2][lr] = wv.z; Ws[lk + 3][lr] = wv.w;
        __syncthreads();
#pragma unroll
        for (int k = 0; k < 8; k++) {
            float4 a0 = *(const float4*)&Xs[k][ty * 8];
            float4 a1 = *(const float4*)&Xs[k][ty * 8 + 4];
            float4 b0 = *(const float4*)&Ws[k][tx * 8];
            float4 b1 = *(const float4*)&Ws[k][tx * 8 + 4];
            float av[8] = {a0.x, a0.y, a0.z, a0.w, a1.x, a1.y, a1.z, a1.w};
            float bv[8] = {b0.x, b0.y, b0.z, b0.w, b1.x, b1.y, b1.z, b1.w};
#pragma unroll
            for (int i = 0; i < 8; i++)
#pragma unroll
                for (int j = 0; j < 8; j++) acc[i][j] += av[i] * bv[j];
        }
    }

#pragma unroll
    for (int i = 0; i < 8; i++) {
        int row = r0 + ty * 8 + i;
        if (row < N) {
            float4 v0 = make_float4(acc[i][0], acc[i][1], acc[i][2], acc[i][3]);
            float4 v1 = make_float4(acc[i][4], acc[i][5], acc[i][6], acc[i][7]);
            *(float4*)&C[(size_t)row * M + c0 + tx * 8] = v0;
            *(float4*)&C[(size_t)row * M + c0 + tx * 8 + 4] = v1;
        }
    }
}

// ---------------- qa[n,h] = sum_f feat[n,h*F+f] * a[f] ----------------
template <int H, int F>
__global__ __launch_bounds__(H * F) void k_qa(const float* __restrict__ feat,
                                              const float* __restrict__ a,
                                              float* __restrict__ qa, int N) {
    constexpr int M = H * F;
    int n = blockIdx.x, t = threadIdx.x;
    __shared__ float s[M];
    float p = feat[(size_t)n * M + t] * a[t & (F - 1)];
    s[t] = p;
    __syncthreads();
    for (int off = F / 2; off > 0; off >>= 1) {
        if ((t & (F - 1)) < off) s[t] += s[t + off];
        __syncthreads();
    }
    if ((t & (F - 1)) == 0) qa[n * H + t / F] = s[t];
}

// ---------------- GAT aggregation: one block per dst node ----------------
template <int H, int F, bool LOUT>
__global__ __launch_bounds__(H * F) void k_agg(const float* __restrict__ feat,
                                               const float* __restrict__ qa,
                                               const float* __restrict__ bias,
                                               const int* __restrict__ rowptr,
                                               const int* __restrict__ csr_src,
                                               const float* __restrict__ csr_lew,
                                               float* __restrict__ out, int N) {
    constexpr int M = H * F;
    int n = blockIdx.x, t = threadIdx.x;
    __shared__ float s_qan[H], s_m[H], s_inv[H];
    __shared__ float red_m[M * H], red_s[M * H];
    __shared__ int sh_src[64];
    __shared__ float sh_alpha[64 * H];

    int beg = rowptr[n];
    int deg = rowptr[n + 1] - beg;
    if (t < H) s_qan[t] = qa[n * H + t];
    __syncthreads();

    // phase 1: online softmax stats per head
    float m_l[H], s_l[H];
#pragma unroll
    for (int h = 0; h < H; h++) { m_l[h] = -1e30f; s_l[h] = 0.f; }
    for (int i = t; i < deg; i += M) {
        int src = csr_src[beg + i];
        float lw = csr_lew[beg + i];
#pragma unroll
        for (int h = 0; h < H; h++) {
            float sc = leaky01(qa[src * H + h] + s_qan[h] + lw);
            if (sc > m_l[h]) {
                s_l[h] = s_l[h] * __expf(m_l[h] - sc) + 1.f;
                m_l[h] = sc;
            } else {
                s_l[h] += __expf(sc - m_l[h]);
            }
        }
    }
#pragma unroll
    for (int h = 0; h < H; h++) { red_m[t * H + h] = m_l[h]; red_s[t * H + h] = s_l[h]; }
    __syncthreads();
    for (int st = M / 2; st > 0; st >>= 1) {
        if (t < st) {
#pragma unroll
            for (int h = 0; h < H; h++) {
                float m1 = red_m[t * H + h], s1 = red_s[t * H + h];
                float m2 = red_m[(t + st) * H + h], s2 = red_s[(t + st) * H + h];
                float mm = fmaxf(m1, m2);
                red_m[t * H + h] = mm;
                red_s[t * H + h] = s1 * __expf(m1 - mm) + s2 * __expf(m2 - mm);
            }
        }
        __syncthreads();
    }
    if (t < H) {
        s_m[t] = red_m[t];
        s_inv[t] = 1.f / fmaxf(red_s[t], 1e-20f);
    }
    __syncthreads();

    // phase 2: weighted aggregation, chunked 64 edges at a time
    float acc = 0.f;
    const int hh = t / F;
    for (int c0 = 0; c0 < deg; c0 += 64) {
        int cn = min(64, deg - c0);
        if (t < cn) {
            int src = csr_src[beg + c0 + t];
            float lw = csr_lew[beg + c0 + t];
            sh_src[t] = src;
#pragma unroll
            for (int h = 0; h < H; h++) {
                float sc = leaky01(qa[src * H + h] + s_qan[h] + lw);
                sh_alpha[t * H + h] = __expf(sc - s_m[h]) * s_inv[h];
            }
        }
        __syncthreads();
        for (int i = 0; i < cn; i++)
            acc += sh_alpha[i * H + hh] * feat[(size_t)sh_src[i] * M + t];
        __syncthreads();
    }
    float r = acc + bias[t];
    if (LOUT) r = leaky01(r);
    out[(size_t)n * M + t] = r;
}

// ---------------- fused predictor: tiled GEMM + small MLP ----------------
// block: 256 threads, 128 pairs. T1 = (h[s]*h[d]) @ W1^T  (tile 128x64, K=128)
// then 64->32->1 in-block via LDS.
__global__ __launch_bounds__(256) void k_predf(const float* __restrict__ h2,
                                               const int* __restrict__ ps, const int* __restrict__ pd,
                                               const int* __restrict__ ns, const int* __restrict__ nd,
                                               const float* __restrict__ W1, const float* __restrict__ b1,
                                               const float* __restrict__ W2, const float* __restrict__ b2,
                                               const float* __restrict__ W3, const float* __restrict__ b3,
                                               float* __restrict__ out, int npos, int ntot) {
    __shared__ float Xs[8][132];     // z tile: [k][pair], pad->bank-safe
    __shared__ float Ws8[8][68];     // W1 tile: [k][out]
    __shared__ float T1s[128][65];   // layer-1 out: [pair][out], pad 65 -> conflict-free rows
    __shared__ float T2s[128][33];   // layer-2 out: [pair][out]

    int t = threadIdx.x;
    int p0 = blockIdx.x * 128;
    int ty = t >> 4, tx = t & 15;    // 16 pair-groups x 16 out-groups

    // A-loader: pair row lr, k-offset lk
    int lr = t >> 1;
    int lk = (t & 1) * 4;
    int pr = p0 + lr;
    int sidx = 0, didx = 0;
    if (pr < ntot) {
        if (pr < npos) { sidx = ps[pr]; didx = pd[pr]; }
        else           { sidx = ns[pr - npos]; didx = nd[pr - npos]; }
    }
    const float* srow = h2 + (size_t)sidx * 128 + lk;
    const float* drow = h2 + (size_t)didx * 128 + lk;

    // W-loader (threads 0..127): out row wr, k-offset wk
    int wr = (t & 127) >> 1;
    int wk = (t & 1) * 4;
    const float* w1row = W1 + (size_t)wr * 128 + wk;

    float acc[8][4];
#pragma unroll
    for (int i = 0; i < 8; i++)
#pragma unroll
        for (int j = 0; j < 4; j++) acc[i][j] = 0.f;

    for (int k0 = 0; k0 < 128; k0 += 8) {
        float4 sv = *(const float4*)(srow + k0);
        float4 dv = *(const float4*)(drow + k0);
        float4 zv = make_float4(sv.x * dv.x, sv.y * dv.y, sv.z * dv.z, sv.w * dv.w);
        float4 wv = make_float4(0.f, 0.f, 0.f, 0.f);
        if (t < 128) wv = *(const float4*)(w1row + k0);
        __syncthreads();
        Xs[lk + 0][lr] = zv.x; Xs[lk + 1][lr] = zv.y; Xs[lk + 2][lr] = zv.z; Xs[lk + 3][lr] = zv.w;
        if (t < 128) { Ws8[wk + 0][wr] = wv.x; Ws8[wk + 1][wr] = wv.y; Ws8[wk + 2][wr] = wv.z; Ws8[wk + 3][wr] = wv.w; }
        __syncthreads();
#pragma unroll
        for (int k = 0; k < 8; k++) {
            float4 a0 = *(const float4*)&Xs[k][ty * 8];
            float4 a1 = *(const float4*)&Xs[k][ty * 8 + 4];
            float4 b0 = *(const float4*)&Ws8[k][tx * 4];
            float av[8] = {a0.x, a0.y, a0.z, a0.w, a1.x, a1.y, a1.z, a1.w};
            float bv[4] = {b0.x, b0.y, b0.z, b0.w};
#pragma unroll
            for (int i = 0; i < 8; i++)
#pragma unroll
                for (int j = 0; j < 4; j++) acc[i][j] += av[i] * bv[j];
        }
    }

    // bias + stash T1 (pre-activation) in LDS
    float bj0 = b1[tx * 4], bj1 = b1[tx * 4 + 1], bj2 = b1[tx * 4 + 2], bj3 = b1[tx * 4 + 3];
#pragma unroll
    for (int i = 0; i < 8; i++) {
        *(float4*)&T1s[ty * 8 + i][tx * 4] =
            make_float4(acc[i][0] + bj0, acc[i][1] + bj1, acc[i][2] + bj2, acc[i][3] + bj3);
    }
    __syncthreads();

    // layer 2: pair = t&127, half (0/1) -> 16 outs each; W2 wave-uniform -> s_load
    int pair = t & 127;
    int half = t >> 7;
    float t2[16];
#pragma unroll
    for (int o = 0; o < 16; o++) t2[o] = b2[half * 16 + o];
    for (int j = 0; j < 64; j += 4) {
        float4 v4 = *(const float4*)&T1s[pair][j];
        float vz0 = leaky02(v4.x), vz1 = leaky02(v4.y), vz2 = leaky02(v4.z), vz3 = leaky02(v4.w);
#pragma unroll
        for (int o = 0; o < 16; o++) {
            const float* w2r = W2 + (size_t)(half * 16 + o) * 64 + j;
            t2[o] += vz0 * w2r[0] + vz1 * w2r[1] + vz2 * w2r[2] + vz3 * w2r[3];
        }
    }
#pragma unroll
    for (int o = 0; o < 16; o += 4)
        *(float4*)&T2s[pair][half * 16 + o] = make_float4(t2[o], t2[o + 1], t2[o + 2], t2[o + 3]);
    __syncthreads();

    // layer 3
    if (t < 128) {
        int pp = p0 + t;
        if (pp < ntot) {
            float o = b3[0];
            for (int j = 0; j < 32; j += 4) {
                float4 v4 = *(const float4*)&T2s[t][j];
                o += leaky02(v4.x) * W3[j] + leaky02(v4.y) * W3[j + 1] +
                     leaky02(v4.z) * W3[j + 2] + leaky02(v4.w) * W3[j + 3];
            }
            out[pp] = o;
        }
    }
}

extern "C" void kernel_launch(void* const* d_in, const int* in_sizes, int n_in,
                              void* d_out, int out_size, void* d_ws, size_t ws_size,
                              hipStream_t stream) {
    const float* x    = (const float*)d_in[0];
    const float* ew   = (const float*)d_in[1];
    const int* esrc   = (const int*)d_in[2];
    const int* edst   = (const int*)d_in[3];
    const int* pos_s  = (const int*)d_in[4];
    const int* pos_d  = (const int*)d_in[5];
    const int* neg_s  = (const int*)d_in[6];
    const int* neg_d  = (const int*)d_in[7];
    const float* W0 = (const float*)d_in[8];
    const float* a0 = (const float*)d_in[9];
    const float* b0 = (const float*)d_in[10];
    const float* W1 = (const float*)d_in[11];
    const float* a1 = (const float*)d_in[12];
    const float* b1 = (const float*)d_in[13];
    const float* W2 = (const float*)d_in[14];
    const float* a2 = (const float*)d_in[15];
    const float* b2 = (const float*)d_in[16];
    const float* pW1 = (const float*)d_in[17];
    const float* pb1 = (const float*)d_in[18];
    const float* pW2 = (const float*)d_in[19];
    const float* pb2 = (const float*)d_in[20];
    const float* pW3 = (const float*)d_in[21];
    const float* pb3 = (const float*)d_in[22];

    const int N = in_sizes[0] / N_IN;   // 25000
    const int E = in_sizes[1];          // 400000
    const int NP = in_sizes[4];         // 100000

    size_t off = 0;
    auto alloc = [&](size_t bytes) {
        void* p = (char*)d_ws + off;
        off += (bytes + 255) & ~(size_t)255;
        return p;
    };
    int* deg      = (int*)alloc((size_t)N * 4);
    int* cursor   = (int*)alloc((size_t)N * 4);
    int* rowptr   = (int*)alloc((size_t)(N + 1) * 4);
    int* csr_eid  = (int*)alloc((size_t)E * 4);
    int* csr_src  = (int*)alloc((size_t)E * 4);
    float* csr_lew = (float*)alloc((size_t)E * 4);
    float* qa     = (float*)alloc((size_t)N * 4 * 4);
    float* A      = (float*)alloc((size_t)N * 256 * 4);
    float* B      = (float*)alloc((size_t)N * 256 * 4);
    (void)ws_size; (void)n_in; (void)out_size;

    float* out_pred = (float*)d_out;              // [200000]
    float* emb      = (float*)d_out + 2 * NP;     // [25000 x 128]

    hipMemsetAsync(deg, 0, (size_t)N * 4, stream);
    hipMemsetAsync(cursor, 0, (size_t)N * 4, stream);

    int eb = (E + 255) / 256;
    k_count<<<eb, 256, 0, stream>>>(edst, deg, E);
    k_scan<<<1, 256, 0, stream>>>(deg, rowptr, N);
    k_fill<<<eb, 256, 0, stream>>>(esrc, edst, ew, rowptr, cursor, csr_eid, csr_src, csr_lew, E);
    k_sortseg<<<(N + 255) / 256, 256, 0, stream>>>(rowptr, csr_eid, csr_src, csr_lew, N);

    int rb = (N + 127) / 128;   // 196

    // layer 0: K=128, M=256
    k_gemm<<<dim3(2, rb), 256, 0, stream>>>(x, W0, A, N, 128, 256);
    k_qa<4, 64><<<N, 256, 0, stream>>>(A, a0, qa, N);
    k_agg<4, 64, true><<<N, 256, 0, stream>>>(A, qa, b0, rowptr, csr_src, csr_lew, B, N);

    // layer 1: K=256, M=256
    k_gemm<<<dim3(2, rb), 256, 0, stream>>>(B, W1, A, N, 256, 256);
    k_qa<4, 64><<<N, 256, 0, stream>>>(A, a1, qa, N);
    k_agg<4, 64, true><<<N, 256, 0, stream>>>(A, qa, b1, rowptr, csr_src, csr_lew, B, N);

    // layer 2: K=256, M=128
    k_gemm<<<dim3(1, rb), 256, 0, stream>>>(B, W2, A, N, 256, 128);
    k_qa<1, 128><<<N, 128, 0, stream>>>(A, a2, qa, N);
    k_agg<1, 128, false><<<N, 128, 0, stream>>>(A, qa, b2, rowptr, csr_src, csr_lew, emb, N);

    // fused predictor on 2*NP pairs
    int ntot = 2 * NP;
    k_predf<<<(ntot + 127) / 128, 256, 0, stream>>>(emb, pos_s, pos_d, neg_s, neg_d,
                                                    pW1, pb1, pW2, pb2, pW3, pb3,
                                                    out_pred, NP, ntot);
}

// Round 3
// 595.791 us; speedup vs baseline: 2.0789x; 1.2507x over previous
//
#include <hip/hip_runtime.h>
#include <math.h>

#define N_IN 128

__device__ __forceinline__ float leaky01(float x) { return x >= 0.f ? x : 0.01f * x; }
__device__ __forceinline__ float leaky02(float x) { return x >= 0.f ? x : 0.2f * x; }

// ---------------- CSR build ----------------
__global__ void k_count(const int* __restrict__ edst, int* __restrict__ deg, int E) {
    int e = blockIdx.x * 256 + threadIdx.x;
    if (e < E) atomicAdd(&deg[edst[e]], 1);
}

// hierarchical scan: per-block inclusive scan + block sums
__global__ void k_scan1(const int* __restrict__ deg, int* __restrict__ rowptr,
                        int* __restrict__ bsum, int n) {
    __shared__ int s[256];
    int b = blockIdx.x, t = threadIdx.x;
    int idx = b * 256 + t;
    int v = (idx < n) ? deg[idx] : 0;
    s[t] = v;
    __syncthreads();
    for (int off = 1; off < 256; off <<= 1) {
        int x = (t >= off) ? s[t - off] : 0;
        __syncthreads();
        s[t] += x;
        __syncthreads();
    }
    if (idx < n) rowptr[idx + 1] = s[t];
    if (t == 255) bsum[b] = s[255];
}

__global__ void k_scan2(const int* __restrict__ bsum, int* __restrict__ boff, int nb) {
    __shared__ int s[128];
    int t = threadIdx.x;
    int v = (t < nb) ? bsum[t] : 0;
    s[t] = v;
    __syncthreads();
    for (int off = 1; off < 128; off <<= 1) {
        int x = (t >= off) ? s[t - off] : 0;
        __syncthreads();
        s[t] += x;
        __syncthreads();
    }
    if (t < nb) boff[t] = s[t] - v;   // exclusive
}

__global__ void k_scan3(int* __restrict__ rowptr, const int* __restrict__ boff, int n) {
    int idx = blockIdx.x * 256 + threadIdx.x;
    if (idx < n) rowptr[idx + 1] += boff[idx >> 8];
    if (idx == 0) rowptr[0] = 0;
}

__global__ void k_fill(const int* __restrict__ esrc, const int* __restrict__ edst,
                       const float* __restrict__ ew, const int* __restrict__ rowptr,
                       int* __restrict__ cursor, int* __restrict__ eid,
                       int* __restrict__ csrc, float* __restrict__ clew, int E) {
    int e = blockIdx.x * 256 + threadIdx.x;
    if (e >= E) return;
    int d = edst[e];
    int slot = rowptr[d] + atomicAdd(&cursor[d], 1);
    eid[slot] = e;
    csrc[slot] = esrc[e];
    clew[slot] = log1pf(ew[e]);
}

// deterministic order: insertion-sort each node's segment by edge id
__global__ void k_sortseg(const int* __restrict__ rowptr, int* __restrict__ eid,
                          int* __restrict__ csrc, float* __restrict__ clew, int n) {
    int v = blockIdx.x * 256 + threadIdx.x;
    if (v >= n) return;
    int b = rowptr[v], e = rowptr[v + 1];
    for (int i = b + 1; i < e; i++) {
        int ke = eid[i], ks = csrc[i];
        float kl = clew[i];
        int j = i - 1;
        while (j >= b && eid[j] > ke) {
            eid[j + 1] = eid[j]; csrc[j + 1] = csrc[j]; clew[j + 1] = clew[j];
            j--;
        }
        eid[j + 1] = ke; csrc[j + 1] = ks; clew[j + 1] = kl;
    }
}

// ---------------- fp32 GEMM: C[N,M] = X[N,K] @ W[M,K]^T, fused qa ----------------
// qa[n,h] = sum_f C[n, h*F+f] * avec[f]; tile covers whole heads (F=64 or 128)
__global__ __launch_bounds__(256) void k_gemm(const float* __restrict__ X,
                                              const float* __restrict__ W,
                                              float* __restrict__ C,
                                              int N, int K, int M,
                                              const float* __restrict__ avec,
                                              float* __restrict__ qaOut,
                                              int H, int F) {
    __shared__ float Xs[8][132];
    __shared__ float Ws[8][132];
    __shared__ float qred[128][17];
    int r0 = blockIdx.y * 128;
    int c0 = blockIdx.x * 128;
    int t = threadIdx.x;
    int ty = t >> 4, tx = t & 15;

    float acc[8][8];
#pragma unroll
    for (int i = 0; i < 8; i++)
#pragma unroll
        for (int j = 0; j < 8; j++) acc[i][j] = 0.f;

    int lr = t >> 1;            // 0..127
    int lk = (t & 1) * 4;       // 0 or 4
    bool xok = (r0 + lr) < N;
    const float* Xp = X + (size_t)(r0 + lr) * K + lk;
    const float* Wp = W + (size_t)(c0 + lr) * K + lk;

    for (int k0 = 0; k0 < K; k0 += 8) {
        float4 xv = xok ? *(const float4*)(Xp + k0) : make_float4(0.f, 0.f, 0.f, 0.f);
        float4 wv = *(const float4*)(Wp + k0);
        __syncthreads();
        Xs[lk + 0][lr] = xv.x; Xs[lk + 1][lr] = xv.y; Xs[lk + 2][lr] = xv.z; Xs[lk + 3][lr] = xv.w;
        Ws[lk + 0][lr] = wv.x; Ws[lk + 1][lr] = wv.y; Ws[lk + 2][lr] = wv.z; Ws[lk + 3][lr] = wv.w;
        __syncthreads();
#pragma unroll
        for (int k = 0; k < 8; k++) {
            float4 a0 = *(const float4*)&Xs[k][ty * 8];
            float4 a1 = *(const float4*)&Xs[k][ty * 8 + 4];
            float4 b0 = *(const float4*)&Ws[k][tx * 8];
            float4 b1 = *(const float4*)&Ws[k][tx * 8 + 4];
            float av[8] = {a0.x, a0.y, a0.z, a0.w, a1.x, a1.y, a1.z, a1.w};
            float bv[8] = {b0.x, b0.y, b0.z, b0.w, b1.x, b1.y, b1.z, b1.w};
#pragma unroll
            for (int i = 0; i < 8; i++)
#pragma unroll
                for (int j = 0; j < 8; j++) acc[i][j] += av[i] * bv[j];
        }
    }

#pragma unroll
    for (int i = 0; i < 8; i++) {
        int row = r0 + ty * 8 + i;
        if (row < N) {
            float4 v0 = make_float4(acc[i][0], acc[i][1], acc[i][2], acc[i][3]);
            float4 v1 = make_float4(acc[i][4], acc[i][5], acc[i][6], acc[i][7]);
            *(float4*)&C[(size_t)row * M + c0 + tx * 8] = v0;
            *(float4*)&C[(size_t)row * M + c0 + tx * 8 + 4] = v1;
        }
    }

    if (qaOut) {
        int f0 = (c0 + tx * 8) & (F - 1);
        float4 a0 = *(const float4*)&avec[f0];
        float4 a1 = *(const float4*)&avec[f0 + 4];
#pragma unroll
        for (int i = 0; i < 8; i++) {
            float s = acc[i][0] * a0.x + acc[i][1] * a0.y + acc[i][2] * a0.z + acc[i][3] * a0.w
                    + acc[i][4] * a1.x + acc[i][5] * a1.y + acc[i][6] * a1.z + acc[i][7] * a1.w;
            qred[ty * 8 + i][tx] = s;
        }
        __syncthreads();
        if (t < 128) {
            int R = r0 + t;
            if (R < N) {
                float s0 = 0.f, s1 = 0.f;
#pragma unroll
                for (int x = 0; x < 8; x++) { s0 += qred[t][x]; s1 += qred[t][x + 8]; }
                if (F == 64) {
                    int hb = c0 >> 6;
                    qaOut[(size_t)R * H + hb] = s0;
                    qaOut[(size_t)R * H + hb + 1] = s1;
                } else {
                    qaOut[R] = s0 + s1;
                }
            }
        }
    }
}

// ---------------- per-node softmax stats + alpha: one wave per node ----------------
template <int H>
__global__ __launch_bounds__(256) void k_stats(const float* __restrict__ qa,
                                               const int* __restrict__ rowptr,
                                               const int* __restrict__ csr_src,
                                               const float* __restrict__ csr_lew,
                                               float* __restrict__ alf, int N) {
    int w = threadIdx.x >> 6;
    int l = threadIdx.x & 63;
    int n = blockIdx.x * 4 + w;
    if (n >= N) return;
    int beg = rowptr[n], end = rowptr[n + 1];
    if (beg >= end) return;

    float qd[H];
#pragma unroll
    for (int h = 0; h < H; h++) qd[h] = qa[(size_t)n * H + h];

    // pass 1: exact max (order-independent)
    float mx[H];
#pragma unroll
    for (int h = 0; h < H; h++) mx[h] = -1e30f;
    for (int i = beg + l; i < end; i += 64) {
        int src = csr_src[i];
        float lw = csr_lew[i];
#pragma unroll
        for (int h = 0; h < H; h++) {
            float sc = leaky01(qa[(size_t)src * H + h] + qd[h] + lw);
            mx[h] = fmaxf(mx[h], sc);
        }
    }
#pragma unroll
    for (int h = 0; h < H; h++) {
        for (int off = 32; off > 0; off >>= 1)
            mx[h] = fmaxf(mx[h], __shfl_xor(mx[h], off, 64));
    }

    // pass 2: sum of exp (fixed-order butterfly -> deterministic)
    float sm[H];
#pragma unroll
    for (int h = 0; h < H; h++) sm[h] = 0.f;
    for (int i = beg + l; i < end; i += 64) {
        int src = csr_src[i];
        float lw = csr_lew[i];
#pragma unroll
        for (int h = 0; h < H; h++) {
            float sc = leaky01(qa[(size_t)src * H + h] + qd[h] + lw);
            sm[h] += __expf(sc - mx[h]);
        }
    }
#pragma unroll
    for (int h = 0; h < H; h++) {
        for (int off = 32; off > 0; off >>= 1)
            sm[h] += __shfl_xor(sm[h], off, 64);
    }
    float inv[H];
#pragma unroll
    for (int h = 0; h < H; h++) inv[h] = 1.f / fmaxf(sm[h], 1e-20f);

    // pass 3: write alpha
    for (int i = beg + l; i < end; i += 64) {
        int src = csr_src[i];
        float lw = csr_lew[i];
        float av[H];
#pragma unroll
        for (int h = 0; h < H; h++) {
            float sc = leaky01(qa[(size_t)src * H + h] + qd[h] + lw);
            av[h] = __expf(sc - mx[h]) * inv[h];
        }
        if (H == 4) {
            *(float4*)&alf[(size_t)i * 4] = make_float4(av[0], av[1], av[2], av[3]);
        } else {
            alf[i] = av[0];
        }
    }
}

// ---------------- weighted aggregation: block per node, pure gather-MAC ----------------
template <int H, int F, bool LOUT>
__global__ __launch_bounds__(H * F) void k_aggw(const float* __restrict__ feat,
                                                const float* __restrict__ alf,
                                                const float* __restrict__ bias,
                                                const int* __restrict__ rowptr,
                                                const int* __restrict__ csr_src,
                                                float* __restrict__ out, int N) {
    constexpr int M = H * F;
    int n = blockIdx.x, t = threadIdx.x;
    __shared__ int sh_src[64];
    __shared__ float sh_alpha[64 * H];

    int beg = rowptr[n];
    int deg = rowptr[n + 1] - beg;
    const int hh = t / F;

    float acc0 = 0.f, acc1 = 0.f;
    for (int c0 = 0; c0 < deg; c0 += 64) {
        int cn = min(64, deg - c0);
        __syncthreads();
        if (t < cn) sh_src[t] = csr_src[beg + c0 + t];
        for (int q = t; q < cn * H; q += M) sh_alpha[q] = alf[(size_t)(beg + c0) * H + q];
        __syncthreads();
        int i = 0;
        for (; i + 2 <= cn; i += 2) {
            float a0 = sh_alpha[i * H + hh];
            float a1 = sh_alpha[(i + 1) * H + hh];
            float f0 = feat[(size_t)sh_src[i] * M + t];
            float f1 = feat[(size_t)sh_src[i + 1] * M + t];
            acc0 += a0 * f0;
            acc1 += a1 * f1;
        }
        if (i < cn) acc0 += sh_alpha[i * H + hh] * feat[(size_t)sh_src[i] * M + t];
    }
    float r = acc0 + acc1 + bias[t];
    if (LOUT) r = leaky01(r);
    out[(size_t)n * M + t] = r;
}

// ---------------- fused predictor v3 ----------------
// 128 threads, 128 pairs/block. Z staged per 32-k chunk with 128B-coalesced loads.
// micro-tile 8x8 (pairs interleaved stride 16), layer2/3 fused.
__global__ __launch_bounds__(128) void k_predf2(const float* __restrict__ h2,
                                                const int* __restrict__ ps, const int* __restrict__ pd,
                                                const int* __restrict__ ns, const int* __restrict__ nd,
                                                const float* __restrict__ W1, const float* __restrict__ b1,
                                                const float* __restrict__ W2, const float* __restrict__ b2,
                                                const float* __restrict__ W3, const float* __restrict__ b3,
                                                float* __restrict__ out, int npos, int ntot) {
    __shared__ float Zs[128 * 36];   // [pair][36] chunk of 32 k, pad->16B-aligned rows
    __shared__ float Wc[32 * 68];    // [k][out]
    __shared__ float T1h[128 * 33];  // half of T1: [pair][32 outs] (pad 33)
    __shared__ int sp[128], dp[128];

    int t = threadIdx.x;
    int p0 = blockIdx.x * 128;
    int ty = t >> 3;        // 0..15 : pair groups (pairs ty + 16*i)
    int tx = t & 7;         // 0..7  : out groups  (outs tx*8 .. +7)

    {
        int pr = p0 + t;
        int s = 0, d = 0;
        if (pr < ntot) {
            if (pr < npos) { s = ps[pr]; d = pd[pr]; }
            else           { s = ns[pr - npos]; d = nd[pr - npos]; }
        }
        sp[t] = s; dp[t] = d;
    }
    __syncthreads();

    float acc[8][8];
#pragma unroll
    for (int i = 0; i < 8; i++)
#pragma unroll
        for (int j = 0; j < 8; j++) acc[i][j] = 0.f;

    for (int kc = 0; kc < 128; kc += 32) {
        // ---- stage Z chunk: 8 sweeps x 16 rows; 8 threads/row, float4 each ----
#pragma unroll
        for (int it = 0; it < 8; ++it) {
            int r = it * 16 + (t >> 3);
            int q = t & 7;
            int s = sp[r], d = dp[r];
            float4 a = *(const float4*)&h2[(size_t)s * 128 + kc + q * 4];
            float4 b = *(const float4*)&h2[(size_t)d * 128 + kc + q * 4];
            *(float4*)&Zs[r * 36 + q * 4] =
                make_float4(a.x * b.x, a.y * b.y, a.z * b.z, a.w * b.w);
        }
        // ---- stage W1 chunk [32 k][64 outs] ----
        {
            int out_ = t & 63;
            int kh = (t >> 6) * 16;
            const float* wr = W1 + (size_t)out_ * 128 + kc + kh;
#pragma unroll
            for (int c = 0; c < 4; c++) {
                float4 wv = *(const float4*)(wr + c * 4);
                Wc[(kh + c * 4 + 0) * 68 + out_] = wv.x;
                Wc[(kh + c * 4 + 1) * 68 + out_] = wv.y;
                Wc[(kh + c * 4 + 2) * 68 + out_] = wv.z;
                Wc[(kh + c * 4 + 3) * 68 + out_] = wv.w;
            }
        }
        __syncthreads();
        // ---- compute 32 k ----
#pragma unroll
        for (int k4 = 0; k4 < 8; ++k4) {
            float4 a4[8];
#pragma unroll
            for (int i = 0; i < 8; i++)
                a4[i] = *(const float4*)&Zs[(ty + 16 * i) * 36 + k4 * 4];
#pragma unroll
            for (int kk = 0; kk < 4; ++kk) {
                float4 bA = *(const float4*)&Wc[(k4 * 4 + kk) * 68 + tx * 8];
                float4 bB = *(const float4*)&Wc[(k4 * 4 + kk) * 68 + tx * 8 + 4];
                float bv[8] = {bA.x, bA.y, bA.z, bA.w, bB.x, bB.y, bB.z, bB.w};
#pragma unroll
                for (int i = 0; i < 8; i++) {
                    float a = (kk == 0) ? a4[i].x : (kk == 1) ? a4[i].y : (kk == 2) ? a4[i].z : a4[i].w;
#pragma unroll
                    for (int j = 0; j < 8; j++) acc[i][j] += a * bv[j];
                }
            }
        }
        __syncthreads();
    }

    // bias (pre-activation kept)
    {
        float4 b1a = *(const float4*)&b1[tx * 8];
        float4 b1b = *(const float4*)&b1[tx * 8 + 4];
        float bb[8] = {b1a.x, b1a.y, b1a.z, b1a.w, b1b.x, b1b.y, b1b.z, b1b.w};
#pragma unroll
        for (int i = 0; i < 8; i++)
#pragma unroll
            for (int j = 0; j < 8; j++) acc[i][j] += bb[j];
    }

    float t2[32];
#pragma unroll
    for (int o = 0; o < 32; o++) t2[o] = b2[o];

    // half 0: outs 0..31 (tx 0..3)
    if (tx < 4) {
#pragma unroll
        for (int i = 0; i < 8; i++)
#pragma unroll
            for (int j = 0; j < 8; j++)
                T1h[(ty + 16 * i) * 33 + tx * 8 + j] = acc[i][j];
    }
    __syncthreads();
    for (int j = 0; j < 32; j += 4) {
        float v0 = leaky02(T1h[t * 33 + j + 0]);
        float v1 = leaky02(T1h[t * 33 + j + 1]);
        float v2 = leaky02(T1h[t * 33 + j + 2]);
        float v3 = leaky02(T1h[t * 33 + j + 3]);
#pragma unroll
        for (int o = 0; o < 32; o++) {
            const float* w2 = W2 + (size_t)o * 64 + j;
            t2[o] += v0 * w2[0] + v1 * w2[1] + v2 * w2[2] + v3 * w2[3];
        }
    }
    __syncthreads();
    // half 1: outs 32..63 (tx 4..7)
    if (tx >= 4) {
#pragma unroll
        for (int i = 0; i < 8; i++)
#pragma unroll
            for (int j = 0; j < 8; j++)
                T1h[(ty + 16 * i) * 33 + (tx - 4) * 8 + j] = acc[i][j];
    }
    __syncthreads();
    for (int j = 0; j < 32; j += 4) {
        float v0 = leaky02(T1h[t * 33 + j + 0]);
        float v1 = leaky02(T1h[t * 33 + j + 1]);
        float v2 = leaky02(T1h[t * 33 + j + 2]);
        float v3 = leaky02(T1h[t * 33 + j + 3]);
#pragma unroll
        for (int o = 0; o < 32; o++) {
            const float* w2 = W2 + (size_t)o * 64 + 32 + j;
            t2[o] += v0 * w2[0] + v1 * w2[1] + v2 * w2[2] + v3 * w2[3];
        }
    }

    float o3 = b3[0];
#pragma unroll
    for (int o = 0; o < 32; o++) o3 += leaky02(t2[o]) * W3[o];
    if (p0 + t < ntot) out[p0 + t] = o3;
}

extern "C" void kernel_launch(void* const* d_in, const int* in_sizes, int n_in,
                              void* d_out, int out_size, void* d_ws, size_t ws_size,
                              hipStream_t stream) {
    const float* x    = (const float*)d_in[0];
    const float* ew   = (const float*)d_in[1];
    const int* esrc   = (const int*)d_in[2];
    const int* edst   = (const int*)d_in[3];
    const int* pos_s  = (const int*)d_in[4];
    const int* pos_d  = (const int*)d_in[5];
    const int* neg_s  = (const int*)d_in[6];
    const int* neg_d  = (const int*)d_in[7];
    const float* W0 = (const float*)d_in[8];
    const float* a0 = (const float*)d_in[9];
    const float* b0 = (const float*)d_in[10];
    const float* W1 = (const float*)d_in[11];
    const float* a1 = (const float*)d_in[12];
    const float* b1 = (const float*)d_in[13];
    const float* W2 = (const float*)d_in[14];
    const float* a2 = (const float*)d_in[15];
    const float* b2 = (const float*)d_in[16];
    const float* pW1 = (const float*)d_in[17];
    const float* pb1 = (const float*)d_in[18];
    const float* pW2 = (const float*)d_in[19];
    const float* pb2 = (const float*)d_in[20];
    const float* pW3 = (const float*)d_in[21];
    const float* pb3 = (const float*)d_in[22];

    const int N = in_sizes[0] / N_IN;   // 25000
    const int E = in_sizes[1];          // 400000
    const int NP = in_sizes[4];         // 100000

    size_t off = 0;
    auto alloc = [&](size_t bytes) {
        void* p = (char*)d_ws + off;
        off += (bytes + 255) & ~(size_t)255;
        return p;
    };
    int* deg      = (int*)alloc((size_t)N * 4);
    int* cursor   = (int*)alloc((size_t)N * 4);
    int* rowptr   = (int*)alloc((size_t)(N + 1) * 4);
    int* bsum     = (int*)alloc(512);
    int* boff     = (int*)alloc(512);
    int* csr_eid  = (int*)alloc((size_t)E * 4);
    int* csr_src  = (int*)alloc((size_t)E * 4);
    float* csr_lew = (float*)alloc((size_t)E * 4);
    float* qa     = (float*)alloc((size_t)N * 4 * 4);
    float* alf    = (float*)alloc((size_t)E * 4 * 4);
    float* A      = (float*)alloc((size_t)N * 256 * 4);
    float* B      = (float*)alloc((size_t)N * 256 * 4);
    (void)ws_size; (void)n_in; (void)out_size;

    float* out_pred = (float*)d_out;              // [200000]
    float* emb      = (float*)d_out + 2 * NP;     // [25000 x 128]

    hipMemsetAsync(deg, 0, (size_t)N * 4, stream);
    hipMemsetAsync(cursor, 0, (size_t)N * 4, stream);

    int eb = (E + 255) / 256;
    int nb = (N + 255) / 256;   // 98
    k_count<<<eb, 256, 0, stream>>>(edst, deg, E);
    k_scan1<<<nb, 256, 0, stream>>>(deg, rowptr, bsum, N);
    k_scan2<<<1, 128, 0, stream>>>(bsum, boff, nb);
    k_scan3<<<nb, 256, 0, stream>>>(rowptr, boff, N);
    k_fill<<<eb, 256, 0, stream>>>(esrc, edst, ew, rowptr, cursor, csr_eid, csr_src, csr_lew, E);
    k_sortseg<<<(N + 255) / 256, 256, 0, stream>>>(rowptr, csr_eid, csr_src, csr_lew, N);

    int rb = (N + 127) / 128;   // 196
    int sb = (N + 3) / 4;       // stats blocks

    // layer 0: K=128, M=256
    k_gemm<<<dim3(2, rb), 256, 0, stream>>>(x, W0, A, N, 128, 256, a0, qa, 4, 64);
    k_stats<4><<<sb, 256, 0, stream>>>(qa, rowptr, csr_src, csr_lew, alf, N);
    k_aggw<4, 64, true><<<N, 256, 0, stream>>>(A, alf, b0, rowptr, csr_src, B, N);

    // layer 1: K=256, M=256
    k_gemm<<<dim3(2, rb), 256, 0, stream>>>(B, W1, A, N, 256, 256, a1, qa, 4, 64);
    k_stats<4><<<sb, 256, 0, stream>>>(qa, rowptr, csr_src, csr_lew, alf, N);
    k_aggw<4, 64, true><<<N, 256, 0, stream>>>(A, alf, b1, rowptr, csr_src, B, N);

    // layer 2: K=256, M=128
    k_gemm<<<dim3(1, rb), 256, 0, stream>>>(B, W2, A, N, 256, 128, a2, qa, 1, 128);
    k_stats<1><<<sb, 256, 0, stream>>>(qa, rowptr, csr_src, csr_lew, alf, N);
    k_aggw<1, 128, false><<<N, 128, 0, stream>>>(A, alf, b2, rowptr, csr_src, emb, N);

    // fused predictor on 2*NP pairs
    int ntot = 2 * NP;
    k_predf2<<<(ntot + 127) / 128, 128, 0, stream>>>(emb, pos_s, pos_d, neg_s, neg_d,
                                                     pW1, pb1, pW2, pb2, pW3, pb3,
                                                     out_pred, NP, ntot);
}

// Round 5
// 560.106 us; speedup vs baseline: 2.2113x; 1.0637x over previous
//
#include <hip/hip_runtime.h>
#include <math.h>

#define N_IN 128

__device__ __forceinline__ float leaky01(float x) { return x >= 0.f ? x : 0.01f * x; }
__device__ __forceinline__ float leaky02(float x) { return x >= 0.f ? x : 0.2f * x; }

// ---------------- CSR build ----------------
__global__ void k_count(const int* __restrict__ edst, int* __restrict__ deg, int E) {
    int e = blockIdx.x * 256 + threadIdx.x;
    if (e < E) atomicAdd(&deg[edst[e]], 1);
}

// hierarchical scan: per-block inclusive scan + block sums
__global__ void k_scan1(const int* __restrict__ deg, int* __restrict__ rowptr,
                        int* __restrict__ bsum, int n) {
    __shared__ int s[256];
    int b = blockIdx.x, t = threadIdx.x;
    int idx = b * 256 + t;
    int v = (idx < n) ? deg[idx] : 0;
    s[t] = v;
    __syncthreads();
    for (int off = 1; off < 256; off <<= 1) {
        int x = (t >= off) ? s[t - off] : 0;
        __syncthreads();
        s[t] += x;
        __syncthreads();
    }
    if (idx < n) rowptr[idx + 1] = s[t];
    if (t == 255) bsum[b] = s[255];
}

__global__ void k_scan2(const int* __restrict__ bsum, int* __restrict__ boff, int nb) {
    __shared__ int s[128];
    int t = threadIdx.x;
    int v = (t < nb) ? bsum[t] : 0;
    s[t] = v;
    __syncthreads();
    for (int off = 1; off < 128; off <<= 1) {
        int x = (t >= off) ? s[t - off] : 0;
        __syncthreads();
        s[t] += x;
        __syncthreads();
    }
    if (t < nb) boff[t] = s[t] - v;   // exclusive
}

__global__ void k_scan3(int* __restrict__ rowptr, const int* __restrict__ boff, int n) {
    int idx = blockIdx.x * 256 + threadIdx.x;
    if (idx < n) rowptr[idx + 1] += boff[idx >> 8];
    if (idx == 0) rowptr[0] = 0;
}

__global__ void k_fill(const int* __restrict__ esrc, const int* __restrict__ edst,
                       const float* __restrict__ ew, const int* __restrict__ rowptr,
                       int* __restrict__ cursor, int* __restrict__ eid,
                       int* __restrict__ csrc, float* __restrict__ clew, int E) {
    int e = blockIdx.x * 256 + threadIdx.x;
    if (e >= E) return;
    int d = edst[e];
    int slot = rowptr[d] + atomicAdd(&cursor[d], 1);
    eid[slot] = e;
    csrc[slot] = esrc[e];
    clew[slot] = log1pf(ew[e]);
}

// deterministic order: insertion-sort each node's segment by edge id
__global__ void k_sortseg(const int* __restrict__ rowptr, int* __restrict__ eid,
                          int* __restrict__ csrc, float* __restrict__ clew, int n) {
    int v = blockIdx.x * 256 + threadIdx.x;
    if (v >= n) return;
    int b = rowptr[v], e = rowptr[v + 1];
    for (int i = b + 1; i < e; i++) {
        int ke = eid[i], ks = csrc[i];
        float kl = clew[i];
        int j = i - 1;
        while (j >= b && eid[j] > ke) {
            eid[j + 1] = eid[j]; csrc[j + 1] = csrc[j]; clew[j + 1] = clew[j];
            j--;
        }
        eid[j + 1] = ke; csrc[j + 1] = ks; clew[j + 1] = kl;
    }
}

// ---------------- fp32 GEMM: C[N,M] = X[N,K] @ W[M,K]^T, fused qa ----------------
__global__ __launch_bounds__(256) void k_gemm(const float* __restrict__ X,
                                              const float* __restrict__ W,
                                              float* __restrict__ C,
                                              int N, int K, int M,
                                              const float* __restrict__ avec,
                                              float* __restrict__ qaOut,
                                              int H, int F) {
    __shared__ float Xs[8][132];
    __shared__ float Ws[8][132];
    __shared__ float qred[128][17];
    int r0 = blockIdx.y * 128;
    int c0 = blockIdx.x * 128;
    int t = threadIdx.x;
    int ty = t >> 4, tx = t & 15;

    float acc[8][8];
#pragma unroll
    for (int i = 0; i < 8; i++)
#pragma unroll
        for (int j = 0; j < 8; j++) acc[i][j] = 0.f;

    int lr = t >> 1;            // 0..127
    int lk = (t & 1) * 4;       // 0 or 4
    bool xok = (r0 + lr) < N;
    const float* Xp = X + (size_t)(r0 + lr) * K + lk;
    const float* Wp = W + (size_t)(c0 + lr) * K + lk;

    for (int k0 = 0; k0 < K; k0 += 8) {
        float4 xv = xok ? *(const float4*)(Xp + k0) : make_float4(0.f, 0.f, 0.f, 0.f);
        float4 wv = *(const float4*)(Wp + k0);
        __syncthreads();
        Xs[lk + 0][lr] = xv.x; Xs[lk + 1][lr] = xv.y; Xs[lk + 2][lr] = xv.z; Xs[lk + 3][lr] = xv.w;
        Ws[lk + 0][lr] = wv.x; Ws[lk + 1][lr] = wv.y; Ws[lk + 2][lr] = wv.z; Ws[lk + 3][lr] = wv.w;
        __syncthreads();
#pragma unroll
        for (int k = 0; k < 8; k++) {
            float4 a0 = *(const float4*)&Xs[k][ty * 8];
            float4 a1 = *(const float4*)&Xs[k][ty * 8 + 4];
            float4 b0 = *(const float4*)&Ws[k][tx * 8];
            float4 b1 = *(const float4*)&Ws[k][tx * 8 + 4];
            float av[8] = {a0.x, a0.y, a0.z, a0.w, a1.x, a1.y, a1.z, a1.w};
            float bv[8] = {b0.x, b0.y, b0.z, b0.w, b1.x, b1.y, b1.z, b1.w};
#pragma unroll
            for (int i = 0; i < 8; i++)
#pragma unroll
                for (int j = 0; j < 8; j++) acc[i][j] += av[i] * bv[j];
        }
    }

#pragma unroll
    for (int i = 0; i < 8; i++) {
        int row = r0 + ty * 8 + i;
        if (row < N) {
            float4 v0 = make_float4(acc[i][0], acc[i][1], acc[i][2], acc[i][3]);
            float4 v1 = make_float4(acc[i][4], acc[i][5], acc[i][6], acc[i][7]);
            *(float4*)&C[(size_t)row * M + c0 + tx * 8] = v0;
            *(float4*)&C[(size_t)row * M + c0 + tx * 8 + 4] = v1;
        }
    }

    if (qaOut) {
        int f0 = (c0 + tx * 8) & (F - 1);
        float4 a0 = *(const float4*)&avec[f0];
        float4 a1 = *(const float4*)&avec[f0 + 4];
#pragma unroll
        for (int i = 0; i < 8; i++) {
            float s = acc[i][0] * a0.x + acc[i][1] * a0.y + acc[i][2] * a0.z + acc[i][3] * a0.w
                    + acc[i][4] * a1.x + acc[i][5] * a1.y + acc[i][6] * a1.z + acc[i][7] * a1.w;
            qred[ty * 8 + i][tx] = s;
        }
        __syncthreads();
        if (t < 128) {
            int R = r0 + t;
            if (R < N) {
                float s0 = 0.f, s1 = 0.f;
#pragma unroll
                for (int x = 0; x < 8; x++) { s0 += qred[t][x]; s1 += qred[t][x + 8]; }
                if (F == 64) {
                    int hb = c0 >> 6;
                    qaOut[(size_t)R * H + hb] = s0;
                    qaOut[(size_t)R * H + hb + 1] = s1;
                } else {
                    qaOut[R] = s0 + s1;
                }
            }
        }
    }
}

// ---------------- per-node softmax stats + alpha: one wave per node ----------------
template <int H>
__global__ __launch_bounds__(256) void k_stats(const float* __restrict__ qa,
                                               const int* __restrict__ rowptr,
                                               const int* __restrict__ csr_src,
                                               const float* __restrict__ csr_lew,
                                               float* __restrict__ alf, int N) {
    int w = threadIdx.x >> 6;
    int l = threadIdx.x & 63;
    int n = blockIdx.x * 4 + w;
    if (n >= N) return;
    int beg = rowptr[n], end = rowptr[n + 1];
    if (beg >= end) return;

    float qd[H];
#pragma unroll
    for (int h = 0; h < H; h++) qd[h] = qa[(size_t)n * H + h];

    float mx[H];
#pragma unroll
    for (int h = 0; h < H; h++) mx[h] = -1e30f;
    for (int i = beg + l; i < end; i += 64) {
        int src = csr_src[i];
        float lw = csr_lew[i];
#pragma unroll
        for (int h = 0; h < H; h++) {
            float sc = leaky01(qa[(size_t)src * H + h] + qd[h] + lw);
            mx[h] = fmaxf(mx[h], sc);
        }
    }
#pragma unroll
    for (int h = 0; h < H; h++) {
        for (int off = 32; off > 0; off >>= 1)
            mx[h] = fmaxf(mx[h], __shfl_xor(mx[h], off, 64));
    }

    float sm[H];
#pragma unroll
    for (int h = 0; h < H; h++) sm[h] = 0.f;
    for (int i = beg + l; i < end; i += 64) {
        int src = csr_src[i];
        float lw = csr_lew[i];
#pragma unroll
        for (int h = 0; h < H; h++) {
            float sc = leaky01(qa[(size_t)src * H + h] + qd[h] + lw);
            sm[h] += __expf(sc - mx[h]);
        }
    }
#pragma unroll
    for (int h = 0; h < H; h++) {
        for (int off = 32; off > 0; off >>= 1)
            sm[h] += __shfl_xor(sm[h], off, 64);
    }
    float inv[H];
#pragma unroll
    for (int h = 0; h < H; h++) inv[h] = 1.f / fmaxf(sm[h], 1e-20f);

    for (int i = beg + l; i < end; i += 64) {
        int src = csr_src[i];
        float lw = csr_lew[i];
        float av[H];
#pragma unroll
        for (int h = 0; h < H; h++) {
            float sc = leaky01(qa[(size_t)src * H + h] + qd[h] + lw);
            av[h] = __expf(sc - mx[h]) * inv[h];
        }
        if (H == 4) {
            *(float4*)&alf[(size_t)i * 4] = make_float4(av[0], av[1], av[2], av[3]);
        } else {
            alf[i] = av[0];
        }
    }
}

// ---------------- weighted aggregation: block per node, pure gather-MAC ----------------
template <int H, int F, bool LOUT>
__global__ __launch_bounds__(H * F) void k_aggw(const float* __restrict__ feat,
                                                const float* __restrict__ alf,
                                                const float* __restrict__ bias,
                                                const int* __restrict__ rowptr,
                                                const int* __restrict__ csr_src,
                                                float* __restrict__ out, int N) {
    constexpr int M = H * F;
    int n = blockIdx.x, t = threadIdx.x;
    __shared__ int sh_src[64];
    __shared__ float sh_alpha[64 * H];

    int beg = rowptr[n];
    int deg = rowptr[n + 1] - beg;
    const int hh = t / F;

    float acc0 = 0.f, acc1 = 0.f;
    for (int c0 = 0; c0 < deg; c0 += 64) {
        int cn = min(64, deg - c0);
        __syncthreads();
        if (t < cn) sh_src[t] = csr_src[beg + c0 + t];
        for (int q = t; q < cn * H; q += M) sh_alpha[q] = alf[(size_t)(beg + c0) * H + q];
        __syncthreads();
        int i = 0;
        for (; i + 2 <= cn; i += 2) {
            float a0 = sh_alpha[i * H + hh];
            float a1 = sh_alpha[(i + 1) * H + hh];
            float f0 = feat[(size_t)sh_src[i] * M + t];
            float f1 = feat[(size_t)sh_src[i + 1] * M + t];
            acc0 += a0 * f0;
            acc1 += a1 * f1;
        }
        if (i < cn) acc0 += sh_alpha[i * H + hh] * feat[(size_t)sh_src[i] * M + t];
    }
    float r = acc0 + acc1 + bias[t];
    if (LOUT) r = leaky01(r);
    out[(size_t)n * M + t] = r;
}

// ---------------- fused predictor v5: 256 threads / 256 pairs ----------------
// micro-tile 8 pairs x 8 outs. Zs (stride 36) reused as T1 in TWO 32-out halves
// (stride 36 only safely holds 32 outs + pad — the v4 bug wrote 64).
__global__ __launch_bounds__(256) void k_predf3(const float* __restrict__ h2,
                                                const int* __restrict__ ps, const int* __restrict__ pd,
                                                const int* __restrict__ ns, const int* __restrict__ nd,
                                                const float* __restrict__ W1, const float* __restrict__ b1,
                                                const float* __restrict__ W2, const float* __restrict__ b2,
                                                const float* __restrict__ W3, const float* __restrict__ b3,
                                                float* __restrict__ out, int npos, int ntot) {
    __shared__ float Zs[256 * 36];   // Z chunk [pair][36]; reused as T1-half [pair][32+pad]
    __shared__ float Wc[32 * 68];    // W1 chunk [k][out]
    __shared__ int sp[256], dp[256];

    int t = threadIdx.x;
    int p0 = blockIdx.x * 256;
    int ty2 = t >> 3;       // 0..31 pair groups: pairs ty2 + 32*i, i<8
    int tx2 = t & 7;        // 0..7 out groups: outs tx2*8..+7

    {
        int pr = p0 + t;
        int s = 0, d = 0;
        if (pr < ntot) {
            if (pr < npos) { s = ps[pr]; d = pd[pr]; }
            else           { s = ns[pr - npos]; d = nd[pr - npos]; }
        }
        sp[t] = s; dp[t] = d;
    }
    __syncthreads();

    float acc[8][8];
#pragma unroll
    for (int i = 0; i < 8; i++)
#pragma unroll
        for (int j = 0; j < 8; j++) acc[i][j] = 0.f;

    int sr = t >> 3;        // staging row within sweep (0..31)
    int sq = t & 7;         // staging quad (0..7)

    for (int kc = 0; kc < 128; kc += 32) {
        // stage Z chunk: 8 sweeps x 32 rows, 8 threads/row (float4 each)
#pragma unroll
        for (int it = 0; it < 8; ++it) {
            int r = it * 32 + sr;
            int s = sp[r], d = dp[r];
            float4 a = *(const float4*)&h2[(size_t)s * 128 + kc + sq * 4];
            float4 b = *(const float4*)&h2[(size_t)d * 128 + kc + sq * 4];
            *(float4*)&Zs[r * 36 + sq * 4] =
                make_float4(a.x * b.x, a.y * b.y, a.z * b.z, a.w * b.w);
        }
        // stage W1 chunk [32 k][64 outs]
        {
            int out_ = t & 63;
            int kh = (t >> 6) * 8;
            const float* wr = W1 + (size_t)out_ * 128 + kc + kh;
#pragma unroll
            for (int c = 0; c < 2; c++) {
                float4 wv = *(const float4*)(wr + c * 4);
                Wc[(kh + c * 4 + 0) * 68 + out_] = wv.x;
                Wc[(kh + c * 4 + 1) * 68 + out_] = wv.y;
                Wc[(kh + c * 4 + 2) * 68 + out_] = wv.z;
                Wc[(kh + c * 4 + 3) * 68 + out_] = wv.w;
            }
        }
        __syncthreads();
#pragma unroll
        for (int k4 = 0; k4 < 8; ++k4) {
            float4 a4[8];
#pragma unroll
            for (int i = 0; i < 8; i++)
                a4[i] = *(const float4*)&Zs[(ty2 + 32 * i) * 36 + k4 * 4];
#pragma unroll
            for (int kk = 0; kk < 4; ++kk) {
                float4 bA = *(const float4*)&Wc[(k4 * 4 + kk) * 68 + tx2 * 8];
                float4 bB = *(const float4*)&Wc[(k4 * 4 + kk) * 68 + tx2 * 8 + 4];
                float bv[8] = {bA.x, bA.y, bA.z, bA.w, bB.x, bB.y, bB.z, bB.w};
#pragma unroll
                for (int i = 0; i < 8; i++) {
                    float a = (kk == 0) ? a4[i].x : (kk == 1) ? a4[i].y : (kk == 2) ? a4[i].z : a4[i].w;
#pragma unroll
                    for (int j = 0; j < 8; j++) acc[i][j] += a * bv[j];
                }
            }
        }
        __syncthreads();
    }

    // bias (pre-activation kept in acc)
    {
        float4 b1a = *(const float4*)&b1[tx2 * 8];
        float4 b1b = *(const float4*)&b1[tx2 * 8 + 4];
        float bb[8] = {b1a.x, b1a.y, b1a.z, b1a.w, b1b.x, b1b.y, b1b.z, b1b.w};
#pragma unroll
        for (int i = 0; i < 8; i++)
#pragma unroll
            for (int j = 0; j < 8; j++) acc[i][j] += bb[j];
    }

    float t2[32];
#pragma unroll
    for (int o = 0; o < 32; o++) t2[o] = b2[o];

    // ---- half A: outs 0..31 (written by tx2 0..3) ----
    if (tx2 < 4) {
#pragma unroll
        for (int i = 0; i < 8; i++) {
            int row = ty2 + 32 * i;
            *(float4*)&Zs[row * 36 + tx2 * 8] =
                make_float4(acc[i][0], acc[i][1], acc[i][2], acc[i][3]);
            *(float4*)&Zs[row * 36 + tx2 * 8 + 4] =
                make_float4(acc[i][4], acc[i][5], acc[i][6], acc[i][7]);
        }
    }
    __syncthreads();
    for (int j = 0; j < 32; j += 4) {
        float4 v4 = *(const float4*)&Zs[t * 36 + j];
        float v0 = leaky02(v4.x), v1 = leaky02(v4.y), v2 = leaky02(v4.z), v3 = leaky02(v4.w);
#pragma unroll
        for (int o = 0; o < 32; o++) {
            const float* w2 = W2 + (size_t)o * 64 + j;
            t2[o] += v0 * w2[0] + v1 * w2[1] + v2 * w2[2] + v3 * w2[3];
        }
    }
    __syncthreads();
    // ---- half B: outs 32..63 (written by tx2 4..7) ----
    if (tx2 >= 4) {
#pragma unroll
        for (int i = 0; i < 8; i++) {
            int row = ty2 + 32 * i;
            *(float4*)&Zs[row * 36 + (tx2 - 4) * 8] =
                make_float4(acc[i][0], acc[i][1], acc[i][2], acc[i][3]);
            *(float4*)&Zs[row * 36 + (tx2 - 4) * 8 + 4] =
                make_float4(acc[i][4], acc[i][5], acc[i][6], acc[i][7]);
        }
    }
    __syncthreads();
    for (int j = 0; j < 32; j += 4) {
        float4 v4 = *(const float4*)&Zs[t * 36 + j];
        float v0 = leaky02(v4.x), v1 = leaky02(v4.y), v2 = leaky02(v4.z), v3 = leaky02(v4.w);
#pragma unroll
        for (int o = 0; o < 32; o++) {
            const float* w2 = W2 + (size_t)o * 64 + 32 + j;
            t2[o] += v0 * w2[0] + v1 * w2[1] + v2 * w2[2] + v3 * w2[3];
        }
    }

    float o3 = b3[0];
#pragma unroll
    for (int o = 0; o < 32; o++) o3 += leaky02(t2[o]) * W3[o];
    if (p0 + t < ntot) out[p0 + t] = o3;
}

extern "C" void kernel_launch(void* const* d_in, const int* in_sizes, int n_in,
                              void* d_out, int out_size, void* d_ws, size_t ws_size,
                              hipStream_t stream) {
    const float* x    = (const float*)d_in[0];
    const float* ew   = (const float*)d_in[1];
    const int* esrc   = (const int*)d_in[2];
    const int* edst   = (const int*)d_in[3];
    const int* pos_s  = (const int*)d_in[4];
    const int* pos_d  = (const int*)d_in[5];
    const int* neg_s  = (const int*)d_in[6];
    const int* neg_d  = (const int*)d_in[7];
    const float* W0 = (const float*)d_in[8];
    const float* a0 = (const float*)d_in[9];
    const float* b0 = (const float*)d_in[10];
    const float* W1 = (const float*)d_in[11];
    const float* a1 = (const float*)d_in[12];
    const float* b1 = (const float*)d_in[13];
    const float* W2 = (const float*)d_in[14];
    const float* a2 = (const float*)d_in[15];
    const float* b2 = (const float*)d_in[16];
    const float* pW1 = (const float*)d_in[17];
    const float* pb1 = (const float*)d_in[18];
    const float* pW2 = (const float*)d_in[19];
    const float* pb2 = (const float*)d_in[20];
    const float* pW3 = (const float*)d_in[21];
    const float* pb3 = (const float*)d_in[22];

    const int N = in_sizes[0] / N_IN;   // 25000
    const int E = in_sizes[1];          // 400000
    const int NP = in_sizes[4];         // 100000

    size_t off = 0;
    auto alloc = [&](size_t bytes) {
        void* p = (char*)d_ws + off;
        off += (bytes + 255) & ~(size_t)255;
        return p;
    };
    int* deg      = (int*)alloc((size_t)N * 4);
    int* cursor   = (int*)alloc((size_t)N * 4);
    int* rowptr   = (int*)alloc((size_t)(N + 1) * 4);
    int* bsum     = (int*)alloc(512);
    int* boff     = (int*)alloc(512);
    int* csr_eid  = (int*)alloc((size_t)E * 4);
    int* csr_src  = (int*)alloc((size_t)E * 4);
    float* csr_lew = (float*)alloc((size_t)E * 4);
    float* qa     = (float*)alloc((size_t)N * 4 * 4);
    float* alf    = (float*)alloc((size_t)E * 4 * 4);
    float* A      = (float*)alloc((size_t)N * 256 * 4);
    float* B      = (float*)alloc((size_t)N * 256 * 4);
    (void)ws_size; (void)n_in; (void)out_size;

    float* out_pred = (float*)d_out;              // [200000]
    float* emb      = (float*)d_out + 2 * NP;     // [25000 x 128]

    hipMemsetAsync(deg, 0, (size_t)N * 4, stream);
    hipMemsetAsync(cursor, 0, (size_t)N * 4, stream);

    int eb = (E + 255) / 256;
    int nb = (N + 255) / 256;   // 98
    k_count<<<eb, 256, 0, stream>>>(edst, deg, E);
    k_scan1<<<nb, 256, 0, stream>>>(deg, rowptr, bsum, N);
    k_scan2<<<1, 128, 0, stream>>>(bsum, boff, nb);
    k_scan3<<<nb, 256, 0, stream>>>(rowptr, boff, N);
    k_fill<<<eb, 256, 0, stream>>>(esrc, edst, ew, rowptr, cursor, csr_eid, csr_src, csr_lew, E);
    k_sortseg<<<(N + 255) / 256, 256, 0, stream>>>(rowptr, csr_eid, csr_src, csr_lew, N);

    int rb = (N + 127) / 128;   // 196
    int sb = (N + 3) / 4;       // stats blocks

    // layer 0: K=128, M=256
    k_gemm<<<dim3(2, rb), 256, 0, stream>>>(x, W0, A, N, 128, 256, a0, qa, 4, 64);
    k_stats<4><<<sb, 256, 0, stream>>>(qa, rowptr, csr_src, csr_lew, alf, N);
    k_aggw<4, 64, true><<<N, 256, 0, stream>>>(A, alf, b0, rowptr, csr_src, B, N);

    // layer 1: K=256, M=256
    k_gemm<<<dim3(2, rb), 256, 0, stream>>>(B, W1, A, N, 256, 256, a1, qa, 4, 64);
    k_stats<4><<<sb, 256, 0, stream>>>(qa, rowptr, csr_src, csr_lew, alf, N);
    k_aggw<4, 64, true><<<N, 256, 0, stream>>>(A, alf, b1, rowptr, csr_src, B, N);

    // layer 2: K=256, M=128
    k_gemm<<<dim3(1, rb), 256, 0, stream>>>(B, W2, A, N, 256, 128, a2, qa, 1, 128);
    k_stats<1><<<sb, 256, 0, stream>>>(qa, rowptr, csr_src, csr_lew, alf, N);
    k_aggw<1, 128, false><<<N, 128, 0, stream>>>(A, alf, b2, rowptr, csr_src, emb, N);

    // fused predictor on 2*NP pairs
    int ntot = 2 * NP;
    k_predf3<<<(ntot + 255) / 256, 256, 0, stream>>>(emb, pos_s, pos_d, neg_s, neg_d,
                                                     pW1, pb1, pW2, pb2, pW3, pb3,
                                                     out_pred, NP, ntot);
}